// Round 8
// baseline (1683.973 us; speedup 1.0000x reference)
//
#include <hip/hip_runtime.h>
#include <math.h>

#define BB 32
#define TT 2048
#define HH 128
#define CHUNK 64
#define NCH (TT / CHUNK)   // 32
#define WS_HDR 4096        // bytes reserved at ws start for handoff flags

// LDS-only barrier: waits LDS ops (lgkmcnt), leaves global loads/stores in
// flight across the barrier.
#define LDS_BARRIER() asm volatile("s_waitcnt lgkmcnt(0)\n\ts_barrier" ::: "memory")

// DPP quad_perm. CTRL = p0|p1<<2|p2<<4|p3<<6. xor1=0xB1, xor2=0x4E,
// broadcast lane q within quad = q*0x55.
#define QPERM_F(v, CTRL)                                                      \
  __int_as_float(__builtin_amdgcn_update_dpp(                                 \
      0, __float_as_int(v), (CTRL), 0xF, 0xF, true))

// ---------------------------------------------------------------------------
// proj kernel: out[r, :] = src_row(r) @ W + bias. GATHER path also zeroes the
// handoff flags (block 0) so the following rnn_pipe sees clean state each
// launch (d_ws is re-poisoned to 0xAA before every timed call).
// ---------------------------------------------------------------------------
template <bool GATHER>
__global__ __launch_bounds__(256) void proj_kernel(
    const float* __restrict__ src, const int* __restrict__ tokens,
    const float* __restrict__ W, const float* __restrict__ bias,
    float* __restrict__ out, int* flags) {
  const int tid = threadIdx.x;
  const int jj = tid & 31;
  const int rr = tid >> 5;
  const int base = blockIdx.x * 64;

  if (GATHER && flags != nullptr && blockIdx.x == 0 && tid < BB)
    flags[tid] = 0;

  __shared__ __align__(16) float srow[64][HH];
  __shared__ int stok[64];

  if (GATHER) {
    if (tid < 64) stok[tid] = tokens[base + tid];
    __syncthreads();
  }

#pragma unroll
  for (int i = 0; i < 8; ++i) {
    int idx = tid + i * 256;
    int row = idx >> 5;
    int c4 = idx & 31;
    const float* s = GATHER ? (src + (size_t)stok[row] * HH)
                            : (src + (size_t)(base + row) * HH);
    *(float4*)&srow[row][c4 * 4] = *(const float4*)&s[c4 * 4];
  }
  __syncthreads();

  float4 b4 = *(const float4*)&bias[jj * 4];
  float4 acc[8];
#pragma unroll
  for (int i = 0; i < 8; ++i) acc[i] = b4;

  for (int k = 0; k < HH; ++k) {
    float4 w4 = *(const float4*)&W[k * HH + jj * 4];
#pragma unroll
    for (int i = 0; i < 8; ++i) {
      float e = srow[rr * 8 + i][k];
      acc[i].x += e * w4.x;
      acc[i].y += e * w4.y;
      acc[i].z += e * w4.z;
      acc[i].w += e * w4.w;
    }
  }

#pragma unroll
  for (int i = 0; i < 8; ++i) {
    int row = base + rr * 8 + i;
    *(float4*)&out[(size_t)row * HH + jj * 4] = acc[i];
  }
}

// ---------------------------------------------------------------------------
// rnn kernel v3 (fallback path; verified 638us/dispatch, 0 conflicts).
// ---------------------------------------------------------------------------
__global__ __launch_bounds__(512) void rnn_kernel(
    float* io, const float* __restrict__ Wh, const int* __restrict__ tokens) {
  const int b = blockIdx.x;
  const int tid = threadIdx.x;
  const int j = tid >> 2;
  const int p = tid & 3;
  const int lane = tid & 63;

  float w[32];
#pragma unroll
  for (int c = 0; c < 32; ++c) {
    int k = 16 * (c >> 2) + 4 * p + (c & 3);
    w[c] = Wh[k * HH + j];
  }

  const int* tok = tokens + b * TT;
  unsigned bits = 0;
#pragma unroll
  for (int i = 0; i < 8; ++i) {
    int4 tk = *(const int4*)&tok[lane * 32 + i * 4];
    bits |= (unsigned)(tk.x != 0) << (i * 4 + 0);
    bits |= (unsigned)(tk.y != 0) << (i * 4 + 1);
    bits |= (unsigned)(tk.z != 0) << (i * 4 + 2);
    bits |= (unsigned)(tk.w != 0) << (i * 4 + 3);
  }

  __shared__ __align__(16) float hs[2][HH];
  if (tid < HH) hs[0][tid] = 0.0f;

  float* xp = io + (size_t)b * TT * HH;
  float h = 0.0f;
  float xc = xp[(size_t)p * HH + j];
  LDS_BARRIER();

#define RNN_STEP(Q)                                                           \
  {                                                                           \
    const int t = t0 + (Q);                                                   \
    const float* hb = hs[(Q) & 1];                                            \
    float a0 = 0.f, a1 = 0.f, a2 = 0.f, a3 = 0.f;                             \
    _Pragma("unroll") for (int i = 0; i < 8; ++i) {                           \
      float4 hv = *(const float4*)&hb[16 * i + 4 * p];                        \
      a0 += hv.x * w[4 * i + 0];                                              \
      a1 += hv.y * w[4 * i + 1];                                              \
      a2 += hv.z * w[4 * i + 2];                                              \
      a3 += hv.w * w[4 * i + 3];                                              \
    }                                                                         \
    float acc = (a0 + a1) + (a2 + a3);                                        \
    acc += QPERM_F(acc, 0xB1);                                                \
    acc += QPERM_F(acc, 0x4E);                                                \
    float sx = acc + QPERM_F(xc, (Q) * 0x55);                                 \
    unsigned word = (unsigned)__builtin_amdgcn_readlane((int)bits, t >> 5);   \
    int m = (word >> (t & 31)) & 1;                                           \
    float e = __expf(-2.0f * fabsf(sx));                                      \
    float th = copysignf((1.0f - e) * __builtin_amdgcn_rcpf(1.0f + e), sx);   \
    h = m ? th : h;                                                           \
    if (p == 0) {                                                             \
      xp[(size_t)t * HH + j] = h;                                             \
      hs[((Q) + 1) & 1][j] = h;                                               \
    }                                                                         \
    LDS_BARRIER();                                                            \
  }

  for (int t0 = 0; t0 < TT; t0 += 4) {
    float xn = 0.0f;
    if (t0 + 4 < TT) xn = xp[(size_t)(t0 + 4 + p) * HH + j];
    RNN_STEP(0)
    RNN_STEP(1)
    RNN_STEP(2)
    RNN_STEP(3)
    xc = xn;
  }
#undef RNN_STEP
}

// ---------------------------------------------------------------------------
// rnn_pipe: both layers concurrently on DIFFERENT CUs (64 blocks of 512).
//   blocks 0..31  (L0, batch b): v3 step on y0buf in-place (xp0 -> y0);
//     after each 64-step chunk: vmcnt(0) drain + barrier + release-store
//     flags[b] = c+1 (agent scope) so L1 can consume.
//   blocks 32..63 (L1, batch b): one chunk behind (waits flags[b] >= c+2).
//     Step folds the input projection: acc = sum(Wh1*h1 + Wx1*y0[t]) with
//     y0 k-slices read from GLOBAL via a distance-2 register ring (VMEM pipe,
//     orthogonal to the LDS-issue bottleneck that binds the step at ~750 cyc).
// No L1->L0 backpressure (y0 buffer is full-size) -> no deadlock; 64 blocks
// << 256 CUs -> co-resident.
// ---------------------------------------------------------------------------
__global__ __launch_bounds__(512) void rnn_pipe(
    float* y0buf, float* __restrict__ out, const float* __restrict__ Wh0,
    const float* __restrict__ Wx1, const float* __restrict__ Wh1,
    const float* __restrict__ b1, const int* __restrict__ tokens,
    int* flags) {
  const int blk = blockIdx.x;
  const bool isL0 = (blk < BB);
  const int b = isL0 ? blk : blk - BB;
  const int tid = threadIdx.x;
  const int j = tid >> 2;
  const int p = tid & 3;
  const int lane = tid & 63;

  // Mask bitmask: lane l holds bits for t in [32l, 32l+32).
  const int* tok = tokens + b * TT;
  unsigned bits = 0;
#pragma unroll
  for (int i = 0; i < 8; ++i) {
    int4 tk = *(const int4*)&tok[lane * 32 + i * 4];
    bits |= (unsigned)(tk.x != 0) << (i * 4 + 0);
    bits |= (unsigned)(tk.y != 0) << (i * 4 + 1);
    bits |= (unsigned)(tk.z != 0) << (i * 4 + 2);
    bits |= (unsigned)(tk.w != 0) << (i * 4 + 3);
  }

  __shared__ __align__(16) float hs[2][HH];
  if (tid < HH) hs[0][tid] = 0.0f;

  float* y0 = y0buf + (size_t)b * TT * HH;

  if (isL0) {
    // ------------------------- layer 0 -------------------------
    float w[32];
#pragma unroll
    for (int c = 0; c < 32; ++c) {
      int k = 16 * (c >> 2) + 4 * p + (c & 3);
      w[c] = Wh0[k * HH + j];
    }
    float h = 0.0f;
    float xc = y0[(size_t)p * HH + j];
    LDS_BARRIER();

#define L0_STEP(Q)                                                            \
  {                                                                           \
    const int t = t0 + (Q);                                                   \
    const float* hb = hs[(Q) & 1];                                            \
    float a0 = 0.f, a1 = 0.f, a2 = 0.f, a3 = 0.f;                             \
    _Pragma("unroll") for (int i = 0; i < 8; ++i) {                           \
      float4 hv = *(const float4*)&hb[16 * i + 4 * p];                        \
      a0 += hv.x * w[4 * i + 0];                                              \
      a1 += hv.y * w[4 * i + 1];                                              \
      a2 += hv.z * w[4 * i + 2];                                              \
      a3 += hv.w * w[4 * i + 3];                                              \
    }                                                                         \
    float acc = (a0 + a1) + (a2 + a3);                                        \
    acc += QPERM_F(acc, 0xB1);                                                \
    acc += QPERM_F(acc, 0x4E);                                                \
    float sx = acc + QPERM_F(xc, (Q) * 0x55);                                 \
    unsigned word = (unsigned)__builtin_amdgcn_readlane((int)bits, t >> 5);   \
    int m = (word >> (t & 31)) & 1;                                           \
    float e = __expf(-2.0f * fabsf(sx));                                      \
    float th = copysignf((1.0f - e) * __builtin_amdgcn_rcpf(1.0f + e), sx);   \
    h = m ? th : h;                                                           \
    if (p == 0) {                                                             \
      y0[(size_t)t * HH + j] = h;                                             \
      hs[((Q) + 1) & 1][j] = h;                                               \
    }                                                                         \
    LDS_BARRIER();                                                            \
  }

    for (int c = 0; c < NCH; ++c) {
      for (int t0 = c * CHUNK; t0 < (c + 1) * CHUNK; t0 += 4) {
        float xn = 0.0f;
        if (t0 + 4 < TT) xn = y0[(size_t)(t0 + 4 + p) * HH + j];
        L0_STEP(0)
        L0_STEP(1)
        L0_STEP(2)
        L0_STEP(3)
        xc = xn;
      }
      // Chunk done: drain own stores, sync all waves (=> all stores in L2),
      // then one lane publishes with agent-scope release (L2 writeback).
      asm volatile("s_waitcnt vmcnt(0)" ::: "memory");
      __syncthreads();
      if (tid == 0) {
        __threadfence();
        __hip_atomic_store(&flags[b], c + 1, __ATOMIC_RELEASE,
                           __HIP_MEMORY_SCOPE_AGENT);
      }
    }
#undef L0_STEP
  } else {
    // ------------------------- layer 1 -------------------------
    float wx[32], wh[32];
#pragma unroll
    for (int c = 0; c < 32; ++c) {
      int k = 16 * (c >> 2) + 4 * p + (c & 3);
      wx[c] = Wx1[k * HH + j];
      wh[c] = Wh1[k * HH + j];
    }
    const float bias1 = b1[j];
    float* ob = out + (size_t)b * TT * HH;
    float h = 0.0f;
    float4 ring0[8], ring1[8];
    LDS_BARRIER();

#define L1_STEP(Q, RG, RGN)                                                   \
  {                                                                           \
    const int t = t0 + (Q);                                                   \
    const float* hb = hs[(Q) & 1];                                            \
    float a0 = 0.f, a1 = 0.f, a2 = 0.f, a3 = 0.f;                             \
    _Pragma("unroll") for (int i = 0; i < 8; ++i) {                           \
      float4 hv = *(const float4*)&hb[16 * i + 4 * p];                        \
      float4 yv = RG[i];                                                      \
      a0 += hv.x * wh[4 * i + 0] + yv.x * wx[4 * i + 0];                      \
      a1 += hv.y * wh[4 * i + 1] + yv.y * wx[4 * i + 1];                      \
      a2 += hv.z * wh[4 * i + 2] + yv.z * wx[4 * i + 2];                      \
      a3 += hv.w * wh[4 * i + 3] + yv.w * wx[4 * i + 3];                      \
    }                                                                         \
    if (t + 2 < TT) {                                                         \
      const float* nsrc = y0 + (size_t)(t + 2) * HH + 4 * p;                  \
      _Pragma("unroll") for (int i = 0; i < 8; ++i)                           \
          RGN[i] = *(const float4*)(nsrc + 16 * i);                           \
    }                                                                         \
    float acc = (a0 + a1) + (a2 + a3);                                        \
    acc += QPERM_F(acc, 0xB1);                                                \
    acc += QPERM_F(acc, 0x4E);                                                \
    float sx = acc + bias1;                                                   \
    unsigned word = (unsigned)__builtin_amdgcn_readlane((int)bits, t >> 5);   \
    int m = (word >> (t & 31)) & 1;                                           \
    float e = __expf(-2.0f * fabsf(sx));                                      \
    float th = copysignf((1.0f - e) * __builtin_amdgcn_rcpf(1.0f + e), sx);   \
    h = m ? th : h;                                                           \
    if (p == 0) {                                                             \
      ob[(size_t)t * HH + j] = h;                                             \
      hs[((Q) + 1) & 1][j] = h;                                               \
    }                                                                         \
    LDS_BARRIER();                                                            \
  }

    for (int c = 0; c < NCH; ++c) {
      const int need = (c + 2 > NCH) ? NCH : (c + 2);
      while (__hip_atomic_load(&flags[b], __ATOMIC_ACQUIRE,
                               __HIP_MEMORY_SCOPE_AGENT) < need)
        __builtin_amdgcn_s_sleep(8);
      if (c == 0) {
        const float* s0 = y0 + 4 * p;
        const float* s1 = y0 + HH + 4 * p;
#pragma unroll
        for (int i = 0; i < 8; ++i) {
          ring0[i] = *(const float4*)(s0 + 16 * i);
          ring1[i] = *(const float4*)(s1 + 16 * i);
        }
      }
      for (int t0 = c * CHUNK; t0 < (c + 1) * CHUNK; t0 += 4) {
        L1_STEP(0, ring0, ring0)
        L1_STEP(1, ring1, ring1)
        L1_STEP(2, ring0, ring0)
        L1_STEP(3, ring1, ring1)
      }
    }
#undef L1_STEP
  }
}

extern "C" void kernel_launch(void* const* d_in, const int* in_sizes, int n_in,
                              void* d_out, int out_size, void* d_ws,
                              size_t ws_size, hipStream_t stream) {
  const int* tokens = (const int*)d_in[0];
  const float* emb = (const float*)d_in[1];
  const float* Wx0 = (const float*)d_in[2];
  const float* Wh0 = (const float*)d_in[3];
  const float* b0 = (const float*)d_in[4];
  const float* Wx1 = (const float*)d_in[5];
  const float* Wh1 = (const float*)d_in[6];
  const float* b1 = (const float*)d_in[7];
  float* out = (float*)d_out;

  const size_t buf_bytes = (size_t)BB * TT * HH * sizeof(float);  // 32 MB
  const int rows = BB * TT;
  const int proj_blocks = rows / 64;

  if (ws_size >= buf_bytes + WS_HDR) {
    // Pipelined path: flags header + xp0/y0 buffer.
    int* flags = (int*)d_ws;
    float* buf = (float*)((char*)d_ws + WS_HDR);
    proj_kernel<true><<<proj_blocks, 256, 0, stream>>>(emb, tokens, Wx0, b0,
                                                       buf, flags);
    rnn_pipe<<<2 * BB, 512, 0, stream>>>(buf, out, Wh0, Wx1, Wh1, b1, tokens,
                                         flags);
  } else {
    // Fallback: verified v3 4-dispatch path.
    float* ws = (float*)d_ws;
    proj_kernel<true><<<proj_blocks, 256, 0, stream>>>(emb, tokens, Wx0, b0,
                                                       ws, nullptr);
    rnn_kernel<<<BB, 512, 0, stream>>>(ws, Wh0, tokens);
    proj_kernel<false><<<proj_blocks, 256, 0, stream>>>(ws, nullptr, Wx1, b1,
                                                        out, nullptr);
    rnn_kernel<<<BB, 512, 0, stream>>>(out, Wh1, tokens);
  }
}